// Round 1
// baseline (586.392 us; speedup 1.0000x reference)
//
#include <hip/hip_runtime.h>
#include <cstdint>
#include <cstddef>

#define N_TOK 8192
#define DIM   1024
#define NEXP  8
#define HID   2816
#define CAP   1280   // int(1.25 * 8192 / 8)

typedef __bf16 bf16x8 __attribute__((ext_vector_type(8)));
typedef float  floatx4 __attribute__((ext_vector_type(4)));
typedef unsigned short u16x8 __attribute__((ext_vector_type(8)));

__device__ __forceinline__ unsigned short f2bf(float f) {
  return __builtin_bit_cast(unsigned short, (__bf16)f);
}

// async global->LDS, 16B per lane. LDS dest must be wave-uniform base + lane*16.
__device__ __forceinline__ void async16(void* lds, const void* g) {
  __builtin_amdgcn_global_load_lds(
      (const __attribute__((address_space(1))) void*)g,
      (__attribute__((address_space(3))) void*)lds, 16, 0, 0);
}

__device__ __forceinline__ void fence_barrier() {
  asm volatile("" ::: "memory");
  __builtin_amdgcn_s_barrier();
  asm volatile("" ::: "memory");
}

// ---------------------------------------------------------------------------
// Routing: FCFS position of each token in its expert queue. One block, 256 thr.
// ---------------------------------------------------------------------------
__global__ void route_kernel(const int* __restrict__ idx, int idx_stride,
                             int* __restrict__ slot,
                             int* __restrict__ slot_token,
                             int* __restrict__ counts) {
  __shared__ int hist[256][NEXP];
  const int t = threadIdx.x;
  int loc[NEXP];
#pragma unroll
  for (int e = 0; e < NEXP; e++) loc[e] = 0;
  const int base = t * 32;
  for (int i = 0; i < 32; i++) {
    int e = idx[(base + i) * idx_stride];
    loc[e]++;
  }
#pragma unroll
  for (int e = 0; e < NEXP; e++) hist[t][e] = loc[e];
  __syncthreads();
  if (t < NEXP) {
    int run = 0;
    for (int i = 0; i < 256; i++) { int v = hist[i][t]; hist[i][t] = run; run += v; }
    counts[t] = run < CAP ? run : CAP;
  }
  __syncthreads();
  int b2[NEXP];
#pragma unroll
  for (int e = 0; e < NEXP; e++) b2[e] = hist[t][e];
  for (int i = 0; i < 32; i++) {
    const int n = base + i;
    const int e = idx[n * idx_stride];
    const int p = b2[e]++;
    if (p < CAP) {
      const int s = e * CAP + p;
      slot[n] = s;
      slot_token[s] = n;
    } else {
      slot[n] = -1;  // dropped -> passthrough
    }
  }
}

// ---------------------------------------------------------------------------
// Dispatch: kept tokens -> bf16 xe[slot]; dropped tokens -> y = x (fp32).
// ---------------------------------------------------------------------------
__global__ void dispatch_kernel(const float* __restrict__ x,
                                const int* __restrict__ slot,
                                unsigned short* __restrict__ xe,
                                float* __restrict__ y) {
  const int n = blockIdx.x;
  const int t = threadIdx.x;
  const int s = slot[n];
  const float4 v = ((const float4*)(x + (size_t)n * DIM))[t];
  if (s >= 0) {
    ushort4 b;
    b.x = f2bf(v.x); b.y = f2bf(v.y); b.z = f2bf(v.z); b.w = f2bf(v.w);
    ((ushort4*)(xe + (size_t)s * DIM))[t] = b;
  } else {
    ((float4*)(y + (size_t)n * DIM))[t] = v;
  }
}

// ---------------------------------------------------------------------------
// Transpose + fp32->bf16: in [E][R][C] fp32 -> out [E][C][R] bf16.
// ---------------------------------------------------------------------------
__global__ __launch_bounds__(256)
void transpose_cvt(const float* __restrict__ in,
                   unsigned short* __restrict__ out,
                   const int R, const int C) {
  __shared__ float tile[64][65];
  const int e = blockIdx.z;
  const float* ib = in + (size_t)e * R * C;
  unsigned short* ob = out + (size_t)e * R * C;
  const int t = threadIdx.x;
  const int c0 = blockIdx.x * 64, r0 = blockIdx.y * 64;
  const int lr = t >> 4;          // 0..15
  const int lc = (t & 15) * 4;    // 0..60
#pragma unroll
  for (int i = 0; i < 4; i++) {
    const float4 v = *(const float4*)(ib + (size_t)(r0 + lr + i * 16) * C + c0 + lc);
    tile[lr + i * 16][lc + 0] = v.x;
    tile[lr + i * 16][lc + 1] = v.y;
    tile[lr + i * 16][lc + 2] = v.z;
    tile[lr + i * 16][lc + 3] = v.w;
  }
  __syncthreads();
  const int oc = t >> 2;          // out row (original col) 0..63
  const int sub = t & 3;
#pragma unroll
  for (int half = 0; half < 2; half++) {
    const int rch = sub + half * 4;  // chunk of 8 original rows
    u16x8 o;
#pragma unroll
    for (int j = 0; j < 8; j++) o[j] = f2bf(tile[rch * 8 + j][oc]);
    *(u16x8*)(ob + (size_t)(c0 + oc) * R + r0 + rch * 8) = o;
  }
}

// ---------------------------------------------------------------------------
// 8-phase GEMM phase primitive (T3+T4+T5).
// One phase = {12 ds_read_b128 ; stage (async global_load_lds) ; s_barrier ;
//              lgkmcnt(0)+sched_barrier ; setprio(1) 16xMFMA setprio(0) ;
//              tail (counted vmcnt at K-tile boundary) ; s_barrier}.
// LDS per unit: [128 rows][64 K] bf16 (128B rows). Chunk swizzle:
// physical 16B chunk = logical ^ (row & 7)  -> conflict-free b128 reads.
// MH selects A-half (rows MH*128..+127 of the 256-row tile).
// ---------------------------------------------------------------------------
template <int MH, int BSTRIDE, class S, class TL>
__device__ __forceinline__ void mm_phase(char* sm, int b, int boff,
                                         int rowA, int rowB, int c0,
                                         floatx4 (&acc)[8][2], S&& stage, TL&& tail) {
  bf16x8 af[4][2], bfr[2][2];
  {
    const char* Ab = sm + b * BSTRIDE + MH * 16384 + rowA;
    const char* Bb = sm + b * BSTRIDE + boff + rowB;
#pragma unroll
    for (int mi = 0; mi < 4; mi++) {
      af[mi][0] = *(const bf16x8*)(Ab + mi * 2048 + c0);
      af[mi][1] = *(const bf16x8*)(Ab + mi * 2048 + (c0 ^ 64));
    }
#pragma unroll
    for (int ni = 0; ni < 2; ni++) {
      bfr[ni][0] = *(const bf16x8*)(Bb + ni * 2048 + c0);
      bfr[ni][1] = *(const bf16x8*)(Bb + ni * 2048 + (c0 ^ 64));
    }
  }
  stage();
  asm volatile("" ::: "memory");
  __builtin_amdgcn_s_barrier();
  asm volatile("s_waitcnt lgkmcnt(0)" ::: "memory");
  __builtin_amdgcn_sched_barrier(0);
  __builtin_amdgcn_s_setprio(1);
#pragma unroll
  for (int mi = 0; mi < 4; mi++)
#pragma unroll
    for (int ni = 0; ni < 2; ni++) {
      acc[MH * 4 + mi][ni] = __builtin_amdgcn_mfma_f32_16x16x32_bf16(
          af[mi][0], bfr[ni][0], acc[MH * 4 + mi][ni], 0, 0, 0);
      acc[MH * 4 + mi][ni] = __builtin_amdgcn_mfma_f32_16x16x32_bf16(
          af[mi][1], bfr[ni][1], acc[MH * 4 + mi][ni], 0, 0, 0);
    }
  __builtin_amdgcn_s_setprio(0);
  tail();
  asm volatile("" ::: "memory");
  __builtin_amdgcn_s_barrier();
  asm volatile("" ::: "memory");
}

// ---------------------------------------------------------------------------
// Fused gate+up grouped GEMM, 8-phase. Tile 256M x 128N (x2 matrices), BK=64.
// 8 waves (2M x 4N): per-wave 128 rows x 32 cols x 2 mats. LDS 128 KiB:
// 2 buffers x {A0 16K | A1 16K | Bg 16K | Bu 16K}. Counted vmcnt(4) once per
// K-tile; stage schedule p0:Bu(T+1) p1:A1(T+1) p2:A0(T+2) p3:Bg(T+2) keeps
// 2 units (4 loads) in flight across every boundary. XCD decode: 5 m-blocks
// of one (n,e) group per XCD.
// ---------------------------------------------------------------------------
__global__ __launch_bounds__(512, 2)
void gateup_gemm8(const unsigned short* __restrict__ A,
                  const unsigned short* __restrict__ Bg,
                  const unsigned short* __restrict__ Bu,
                  const int* __restrict__ counts,
                  unsigned short* __restrict__ hact) {
  extern __shared__ __align__(16) char smem[];
  // grid 880 = 8 xcd * (22 cgl * 5 m)
  const int bid = blockIdx.x;
  const int xcd = bid & 7;
  const int slotb = bid >> 3;      // 0..109
  const int m = slotb % 5;
  const int cgl = slotb / 5;       // 0..21
  const int cg = xcd + 8 * cgl;    // 0..175
  const int n = cg % 22;
  const int e = cg / 22;

  const int cnt = counts[e];
  const int m0 = m * 256;
  if (m0 >= cnt) return;
  const int n0 = n * 128;

  const int t = threadIdx.x;
  const int lane = t & 63;
  const int w = t >> 6;
  const int wr = w >> 2;     // 0..1 : 64-row slice within each A-half
  const int wc = w & 3;      // 0..3 : 32-col slice
  const int li = lane & 15;
  const int q = lane >> 4;

  // staging: LDS linear slot (r = l*64 + t>>3, chunk t&7); source chunk
  // pre-swizzled so LDS(r, c) = global(r, c ^ (r&7)).
  const int sr8 = t >> 3;
  const int cLog = (t & 7) ^ (sr8 & 7);
  const unsigned short* aB  = A  + ((size_t)e * CAP + m0 + sr8) * DIM + cLog * 8;
  const unsigned short* bgB = Bg + ((size_t)e * HID + n0 + sr8) * DIM + cLog * 8;
  const unsigned short* buB = Bu + ((size_t)e * HID + n0 + sr8) * DIM + cLog * 8;

  auto stageU = [&](int bb, int uoff, const unsigned short* s0, const unsigned short* s1) {
    async16(smem + bb * 65536 + uoff + t * 16, s0);
    async16(smem + bb * 65536 + uoff + 8192 + t * 16, s1);
  };

  const int rowA = (wr * 64 + li) * 128;
  const int rowB = (wc * 32 + li) * 128;
  const int c0 = (q ^ (li & 7)) * 16;

  floatx4 accg[8][2] = {};
  floatx4 accu[8][2] = {};

  constexpr int NT = DIM / 64;  // 16 K-tiles

  // prologue: tile0 {A0,Bg,Bu,A1} + tile1 {A0,Bg} = 12 loads; wait oldest 8.
  stageU(0, 0,     aB,                     aB + (size_t)64 * DIM);
  stageU(0, 32768, bgB,                    bgB + (size_t)64 * DIM);
  stageU(0, 49152, buB,                    buB + (size_t)64 * DIM);
  stageU(0, 16384, aB + (size_t)128 * DIM, aB + (size_t)192 * DIM);
  stageU(1, 0,     aB + 64,                aB + (size_t)64 * DIM + 64);
  stageU(1, 32768, bgB + 64,               bgB + (size_t)64 * DIM + 64);
  asm volatile("s_waitcnt vmcnt(4)" ::: "memory");
  fence_barrier();

#pragma unroll 2
  for (int T = 0; T < NT; T++) {
    const int b = T & 1;
    const int bn = b ^ 1;
    // p0: A0 x Bg | stage Bu(T+1)
    mm_phase<0, 65536>(smem, b, 32768, rowA, rowB, c0, accg,
        [&] {
          if (T + 1 < NT)
            stageU(bn, 49152, buB + (T + 1) * 64,
                              buB + (size_t)64 * DIM + (T + 1) * 64);
        }, [] {});
    // p1: A0 x Bu | stage A1(T+1)
    mm_phase<0, 65536>(smem, b, 49152, rowA, rowB, c0, accu,
        [&] {
          if (T + 1 < NT)
            stageU(bn, 16384, aB + (size_t)128 * DIM + (T + 1) * 64,
                              aB + (size_t)192 * DIM + (T + 1) * 64);
        }, [] {});
    // p2: A1 x Bg | stage A0(T+2)
    mm_phase<1, 65536>(smem, b, 32768, rowA, rowB, c0, accg,
        [&] {
          if (T + 2 < NT)
            stageU(b, 0, aB + (T + 2) * 64,
                         aB + (size_t)64 * DIM + (T + 2) * 64);
        }, [] {});
    // p3: A1 x Bu | stage Bg(T+2) ; counted vmcnt at tile boundary
    mm_phase<1, 65536>(smem, b, 49152, rowA, rowB, c0, accu,
        [&] {
          if (T + 2 < NT)
            stageU(b, 32768, bgB + (T + 2) * 64,
                             bgB + (size_t)64 * DIM + (T + 2) * 64);
        },
        [&] {
          if (T + 2 < NT)
            asm volatile("s_waitcnt vmcnt(4)" ::: "memory");
          else if (T + 1 < NT)
            asm volatile("s_waitcnt vmcnt(0)" ::: "memory");
        });
  }

  // epilogue: hact = silu(g)*u. C/D: col = lane&15, row = (lane>>4)*4 + reg.
  unsigned short* ob = hact + (size_t)e * CAP * HID;
#pragma unroll
  for (int mh = 0; mh < 2; mh++)
#pragma unroll
    for (int mi = 0; mi < 4; mi++)
#pragma unroll
      for (int r = 0; r < 4; r++) {
        const int row = m0 + mh * 128 + wr * 64 + mi * 16 + q * 4 + r;
        const size_t rb = (size_t)row * HID;
#pragma unroll
        for (int ni = 0; ni < 2; ni++) {
          const int col = n0 + wc * 32 + ni * 16 + li;
          const float g = accg[mh * 4 + mi][ni][r];
          const float u = accu[mh * 4 + mi][ni][r];
          ob[rb + col] = f2bf(g / (1.0f + __expf(-g)) * u);
        }
      }
}

// ---------------------------------------------------------------------------
// Down GEMM + fused gather/scale, 8-phase style (2 phases per K-tile).
// Tile 256M x 128N, BK=64, 8 waves, LDS 96 KiB: 2 x {A0 16K | A1 16K | B 16K}.
// Counted vmcnt(2) per K-tile. Grid 320 (~256 active at cnt~1024).
// ---------------------------------------------------------------------------
__global__ __launch_bounds__(512, 2)
void down_gemm8(const unsigned short* __restrict__ A,
                const unsigned short* __restrict__ Bt,
                const int* __restrict__ counts,
                const int* __restrict__ slot_token,
                const float* __restrict__ scores,
                float* __restrict__ y) {
  extern __shared__ __align__(16) char smem[];
  // grid 320 = 8 xcd * (8 cgl * 5 m)
  const int bid = blockIdx.x;
  const int xcd = bid & 7;
  const int slotb = bid >> 3;      // 0..39
  const int m = slotb % 5;
  const int cgl = slotb / 5;       // 0..7
  const int cg = xcd + 8 * cgl;    // 0..63
  const int n = cg % 8;
  const int e = cg / 8;

  const int cnt = counts[e];
  const int m0 = m * 256;
  if (m0 >= cnt) return;
  const int n0 = n * 128;

  const int t = threadIdx.x;
  const int lane = t & 63;
  const int w = t >> 6;
  const int wr = w >> 2;
  const int wc = w & 3;
  const int li = lane & 15;
  const int q = lane >> 4;

  const int sr8 = t >> 3;
  const int cLog = (t & 7) ^ (sr8 & 7);
  const unsigned short* aB = A  + ((size_t)e * CAP + m0 + sr8) * HID + cLog * 8;
  const unsigned short* bB = Bt + ((size_t)e * DIM + n0 + sr8) * HID + cLog * 8;

  auto stageU = [&](int bb, int uoff, const unsigned short* s0, const unsigned short* s1) {
    async16(smem + bb * 49152 + uoff + t * 16, s0);
    async16(smem + bb * 49152 + uoff + 8192 + t * 16, s1);
  };

  const int rowA = (wr * 64 + li) * 128;
  const int rowB = (wc * 32 + li) * 128;
  const int c0 = (q ^ (li & 7)) * 16;

  floatx4 acc[8][2] = {};

  constexpr int NT = HID / 64;  // 44 K-tiles

  // prologue: tile0 {A0,B,A1} + tile1 {A0} = 8 loads; wait oldest 6.
  stageU(0, 0,     aB,                     aB + (size_t)64 * HID);
  stageU(0, 32768, bB,                     bB + (size_t)64 * HID);
  stageU(0, 16384, aB + (size_t)128 * HID, aB + (size_t)192 * HID);
  stageU(1, 0,     aB + 64,                aB + (size_t)64 * HID + 64);
  asm volatile("s_waitcnt vmcnt(2)" ::: "memory");
  fence_barrier();

#pragma unroll 2
  for (int T = 0; T < NT; T++) {
    const int b = T & 1;
    const int bn = b ^ 1;
    // p0: A0 x B | stage {A1,B}(T+1)
    mm_phase<0, 49152>(smem, b, 32768, rowA, rowB, c0, acc,
        [&] {
          if (T + 1 < NT) {
            stageU(bn, 16384, aB + (size_t)128 * HID + (T + 1) * 64,
                              aB + (size_t)192 * HID + (T + 1) * 64);
            stageU(bn, 32768, bB + (T + 1) * 64,
                              bB + (size_t)64 * HID + (T + 1) * 64);
          }
        }, [] {});
    // p1: A1 x B | stage A0(T+2) ; counted vmcnt at tile boundary
    mm_phase<1, 49152>(smem, b, 32768, rowA, rowB, c0, acc,
        [&] {
          if (T + 2 < NT)
            stageU(b, 0, aB + (T + 2) * 64,
                         aB + (size_t)64 * HID + (T + 2) * 64);
        },
        [&] {
          if (T + 2 < NT)
            asm volatile("s_waitcnt vmcnt(2)" ::: "memory");
          else if (T + 1 < NT)
            asm volatile("s_waitcnt vmcnt(0)" ::: "memory");
        });
  }

  // epilogue: y[tok] = acc * score (row < cnt only)
#pragma unroll
  for (int mh = 0; mh < 2; mh++)
#pragma unroll
    for (int mi = 0; mi < 4; mi++)
#pragma unroll
      for (int r = 0; r < 4; r++) {
        const int row = m0 + mh * 128 + wr * 64 + mi * 16 + q * 4 + r;
        if (row < cnt) {
          const int tok = slot_token[e * CAP + row];
          const float s = scores[tok];
          float* yr = y + (size_t)tok * DIM;
#pragma unroll
          for (int ni = 0; ni < 2; ni++) {
            const int col = n0 + wc * 32 + ni * 16 + li;
            yr[col] = acc[mh * 4 + mi][ni][r] * s;
          }
        }
      }
}

extern "C" void kernel_launch(void* const* d_in, const int* in_sizes, int n_in,
                              void* d_out, int out_size, void* d_ws, size_t ws_size,
                              hipStream_t stream) {
  const float* x      = (const float*)d_in[0];
  const int*   idx    = (const int*)d_in[1];
  const float* scores = (const float*)d_in[2];
  const float* Wg     = (const float*)d_in[3];
  const float* Wu     = (const float*)d_in[4];
  const float* Wd     = (const float*)d_in[5];
  float* y = (float*)d_out;

  const int idx_stride = (in_sizes[1] == 2 * N_TOK) ? 2 : 1;

  char* ws = (char*)d_ws;
  size_t off = 0;
  auto alloc = [&](size_t b) -> char* {
    char* p = ws + off;
    off += (b + 255) & ~(size_t)255;
    return p;
  };
  int* counts            = (int*)alloc(NEXP * 4);
  int* slot              = (int*)alloc((size_t)N_TOK * 4);
  int* slot_token        = (int*)alloc((size_t)NEXP * CAP * 4);
  unsigned short* xe     = (unsigned short*)alloc((size_t)NEXP * CAP * DIM * 2);
  unsigned short* hact   = (unsigned short*)alloc((size_t)NEXP * CAP * HID * 2);
  unsigned short* wg_t   = (unsigned short*)alloc((size_t)NEXP * DIM * HID * 2);
  unsigned short* wu_t   = (unsigned short*)alloc((size_t)NEXP * DIM * HID * 2);
  unsigned short* wd_t   = (unsigned short*)alloc((size_t)NEXP * DIM * HID * 2);
  (void)ws_size; (void)n_in; (void)out_size;

  static bool s_attr_done = false;
  if (!s_attr_done) {
    hipFuncSetAttribute((const void*)gateup_gemm8,
                        hipFuncAttributeMaxDynamicSharedMemorySize, 131072);
    hipFuncSetAttribute((const void*)down_gemm8,
                        hipFuncAttributeMaxDynamicSharedMemorySize, 98304);
    s_attr_done = true;
  }

  route_kernel<<<1, 256, 0, stream>>>(idx, idx_stride, slot, slot_token, counts);
  dispatch_kernel<<<N_TOK, 256, 0, stream>>>(x, slot, xe, y);

  // Wg,Wu: [d][h] -> [h][d] bf16 ;  Wd: [h][d] -> [d][h] bf16
  transpose_cvt<<<dim3(HID / 64, DIM / 64, NEXP), 256, 0, stream>>>(Wg, wg_t, DIM, HID);
  transpose_cvt<<<dim3(HID / 64, DIM / 64, NEXP), 256, 0, stream>>>(Wu, wu_t, DIM, HID);
  transpose_cvt<<<dim3(DIM / 64, HID / 64, NEXP), 256, 0, stream>>>(Wd, wd_t, HID, DIM);

  // fused gate+up: hact = silu(xe@Wg) * (xe@Wu)   [8-phase, counted vmcnt]
  gateup_gemm8<<<8 * 22 * 5, 512, 131072, stream>>>(xe, wg_t, wu_t, counts, hact);
  // down + fused gather/scale: y[tok] = (hact @ Wd) * score
  down_gemm8<<<8 * 8 * 5, 512, 98304, stream>>>(hact, wd_t, counts, slot_token, scores, y);
}

// Round 2
// 548.955 us; speedup vs baseline: 1.0682x; 1.0682x over previous
//
#include <hip/hip_runtime.h>
#include <cstdint>
#include <cstddef>

#define N_TOK 8192
#define DIM   1024
#define NEXP  8
#define HID   2816
#define CAP   1280   // int(1.25 * 8192 / 8)

typedef __bf16 bf16x8 __attribute__((ext_vector_type(8)));
typedef float  floatx4 __attribute__((ext_vector_type(4)));
typedef unsigned short u16x8 __attribute__((ext_vector_type(8)));

__device__ __forceinline__ unsigned short f2bf(float f) {
  return __builtin_bit_cast(unsigned short, (__bf16)f);
}

// async global->LDS, 16B per lane. LDS dest must be wave-uniform base + lane*16.
__device__ __forceinline__ void async16(void* lds, const void* g) {
  __builtin_amdgcn_global_load_lds(
      (const __attribute__((address_space(1))) void*)g,
      (__attribute__((address_space(3))) void*)lds, 16, 0, 0);
}

__device__ __forceinline__ void fence_barrier() {
  asm volatile("" ::: "memory");
  __builtin_amdgcn_s_barrier();
  asm volatile("" ::: "memory");
}

__device__ __forceinline__ floatx4 mfma16(bf16x8 a, bf16x8 b, floatx4 c) {
  return __builtin_amdgcn_mfma_f32_16x16x32_bf16(a, b, c, 0, 0, 0);
}

// ---------------------------------------------------------------------------
// Routing: FCFS position of each token in its expert queue. One block, 256 thr.
// ---------------------------------------------------------------------------
__global__ void route_kernel(const int* __restrict__ idx, int idx_stride,
                             int* __restrict__ slot,
                             int* __restrict__ slot_token,
                             int* __restrict__ counts) {
  __shared__ int hist[256][NEXP];
  const int t = threadIdx.x;
  int loc[NEXP];
#pragma unroll
  for (int e = 0; e < NEXP; e++) loc[e] = 0;
  const int base = t * 32;
  for (int i = 0; i < 32; i++) {
    int e = idx[(base + i) * idx_stride];
    loc[e]++;
  }
#pragma unroll
  for (int e = 0; e < NEXP; e++) hist[t][e] = loc[e];
  __syncthreads();
  if (t < NEXP) {
    int run = 0;
    for (int i = 0; i < 256; i++) { int v = hist[i][t]; hist[i][t] = run; run += v; }
    counts[t] = run < CAP ? run : CAP;
  }
  __syncthreads();
  int b2[NEXP];
#pragma unroll
  for (int e = 0; e < NEXP; e++) b2[e] = hist[t][e];
  for (int i = 0; i < 32; i++) {
    const int n = base + i;
    const int e = idx[n * idx_stride];
    const int p = b2[e]++;
    if (p < CAP) {
      const int s = e * CAP + p;
      slot[n] = s;
      slot_token[s] = n;
    } else {
      slot[n] = -1;  // dropped -> passthrough
    }
  }
}

// ---------------------------------------------------------------------------
// Dispatch: kept tokens -> bf16 xe[slot]; dropped tokens -> y = x (fp32).
// ---------------------------------------------------------------------------
__global__ void dispatch_kernel(const float* __restrict__ x,
                                const int* __restrict__ slot,
                                unsigned short* __restrict__ xe,
                                float* __restrict__ y) {
  const int n = blockIdx.x;
  const int t = threadIdx.x;
  const int s = slot[n];
  const float4 v = ((const float4*)(x + (size_t)n * DIM))[t];
  if (s >= 0) {
    ushort4 b;
    b.x = f2bf(v.x); b.y = f2bf(v.y); b.z = f2bf(v.z); b.w = f2bf(v.w);
    ((ushort4*)(xe + (size_t)s * DIM))[t] = b;
  } else {
    ((float4*)(y + (size_t)n * DIM))[t] = v;
  }
}

// ---------------------------------------------------------------------------
// Transpose + fp32->bf16: in [E][R][C] fp32 -> out [E][C][R] bf16.
// ---------------------------------------------------------------------------
__global__ __launch_bounds__(256)
void transpose_cvt(const float* __restrict__ in,
                   unsigned short* __restrict__ out,
                   const int R, const int C) {
  __shared__ float tile[64][65];
  const int e = blockIdx.z;
  const float* ib = in + (size_t)e * R * C;
  unsigned short* ob = out + (size_t)e * R * C;
  const int t = threadIdx.x;
  const int c0 = blockIdx.x * 64, r0 = blockIdx.y * 64;
  const int lr = t >> 4;          // 0..15
  const int lc = (t & 15) * 4;    // 0..60
#pragma unroll
  for (int i = 0; i < 4; i++) {
    const float4 v = *(const float4*)(ib + (size_t)(r0 + lr + i * 16) * C + c0 + lc);
    tile[lr + i * 16][lc + 0] = v.x;
    tile[lr + i * 16][lc + 1] = v.y;
    tile[lr + i * 16][lc + 2] = v.z;
    tile[lr + i * 16][lc + 3] = v.w;
  }
  __syncthreads();
  const int oc = t >> 2;          // out row (original col) 0..63
  const int sub = t & 3;
#pragma unroll
  for (int half = 0; half < 2; half++) {
    const int rch = sub + half * 4;  // chunk of 8 original rows
    u16x8 o;
#pragma unroll
    for (int j = 0; j < 8; j++) o[j] = f2bf(tile[rch * 8 + j][oc]);
    *(u16x8*)(ob + (size_t)(c0 + oc) * R + r0 + rch * 8) = o;
  }
}

// ---------------------------------------------------------------------------
// Fused gate+up grouped GEMM. Tile 256M x 128N (x2 matrices), BK=64, 8 waves
// (2 wr x 4 wc), per-wave 128 rows x 32 cols x 2 mats. READ-ONCE discipline:
// per K-tile each wave reads A 16 + Bg 4 + Bu 4 = 24 b128 (B frags cached in
// registers across the two phases, A halves read once each). 2 phases/K-tile,
// 32 MFMA per barrier. LDS 128 KiB: 2 buf x {A0 16K | A1 16K | Bg 16K | Bu 16K}.
// Counted vmcnt: p0 tail vmcnt(6) [needs A1(T)], p1 tail vmcnt(4) [needs
// A0/Bg/Bu(T+1)]; stage schedule p0: Bg,Bu(T+1)->bn ; p1: A1(T+1)->bn,
// A0(T+2)->b. Chunk swizzle: LDS(r, c) = global(r, c ^ (r&7)).
// ---------------------------------------------------------------------------
__global__ __launch_bounds__(512, 2)
void gateup_gemm2(const unsigned short* __restrict__ A,
                  const unsigned short* __restrict__ Bg,
                  const unsigned short* __restrict__ Bu,
                  const int* __restrict__ counts,
                  unsigned short* __restrict__ hact) {
  extern __shared__ __align__(16) char smem[];
  // grid 880 = 8 xcd * (22 cgl * 5 m)
  const int bid = blockIdx.x;
  const int xcd = bid & 7;
  const int slotb = bid >> 3;      // 0..109
  const int m = slotb % 5;
  const int cgl = slotb / 5;       // 0..21
  const int cg = xcd + 8 * cgl;    // 0..175
  const int n = cg % 22;
  const int e = cg / 22;

  const int cnt = counts[e];
  const int m0 = m * 256;
  if (m0 >= cnt) return;
  const int n0 = n * 128;

  const int t = threadIdx.x;
  const int lane = t & 63;
  const int w = t >> 6;
  const int wr = w >> 2;     // 0..1
  const int wc = w & 3;      // 0..3
  const int li = lane & 15;
  const int q = lane >> 4;

  const int sr8 = t >> 3;
  const int cLog = (t & 7) ^ (sr8 & 7);
  const unsigned short* aB  = A  + ((size_t)e * CAP + m0 + sr8) * DIM + cLog * 8;
  const unsigned short* bgB = Bg + ((size_t)e * HID + n0 + sr8) * DIM + cLog * 8;
  const unsigned short* buB = Bu + ((size_t)e * HID + n0 + sr8) * DIM + cLog * 8;

  auto stageU = [&](int bb, int uoff, const unsigned short* s0, const unsigned short* s1) {
    async16(smem + bb * 65536 + uoff + t * 16, s0);
    async16(smem + bb * 65536 + uoff + 8192 + t * 16, s1);
  };

  const int rowA = (wr * 64 + li) * 128;
  const int rowB = (wc * 32 + li) * 128;
  const int c0 = (q ^ (li & 7)) * 16;

  floatx4 accg[8][2] = {};
  floatx4 accu[8][2] = {};

  constexpr int NT = DIM / 64;  // 16 K-tiles

  // prologue: A0(0),Bg(0),Bu(0) [6 oldest] + A1(0) [2] + A0(1) [2]; wait 6.
  stageU(0, 0,     aB,                     aB + (size_t)64 * DIM);
  stageU(0, 32768, bgB,                    bgB + (size_t)64 * DIM);
  stageU(0, 49152, buB,                    buB + (size_t)64 * DIM);
  stageU(0, 16384, aB + (size_t)128 * DIM, aB + (size_t)192 * DIM);
  stageU(1, 0,     aB + 64,                aB + (size_t)64 * DIM + 64);
  asm volatile("s_waitcnt vmcnt(4)" ::: "memory");
  fence_barrier();

#pragma unroll 2
  for (int T = 0; T < NT; T++) {
    const int b = T & 1;
    const int bn = b ^ 1;
    char* sb = smem + b * 65536;
    bf16x8 bgf[2][2], buf2[2][2];
    // ---- phase 0: A-half 0, read Bg/Bu once and cache ----
    {
      bf16x8 af[4][2];
#pragma unroll
      for (int mi = 0; mi < 4; mi++) {
        af[mi][0] = *(const bf16x8*)(sb + rowA + mi * 2048 + c0);
        af[mi][1] = *(const bf16x8*)(sb + rowA + mi * 2048 + (c0 ^ 64));
      }
#pragma unroll
      for (int ni = 0; ni < 2; ni++) {
        bgf[ni][0]  = *(const bf16x8*)(sb + 32768 + rowB + ni * 2048 + c0);
        bgf[ni][1]  = *(const bf16x8*)(sb + 32768 + rowB + ni * 2048 + (c0 ^ 64));
        buf2[ni][0] = *(const bf16x8*)(sb + 49152 + rowB + ni * 2048 + c0);
        buf2[ni][1] = *(const bf16x8*)(sb + 49152 + rowB + ni * 2048 + (c0 ^ 64));
      }
      if (T + 1 < NT) {
        stageU(bn, 32768, bgB + (T + 1) * 64, bgB + (size_t)64 * DIM + (T + 1) * 64);
        stageU(bn, 49152, buB + (T + 1) * 64, buB + (size_t)64 * DIM + (T + 1) * 64);
      }
      asm volatile("" ::: "memory");
      __builtin_amdgcn_s_barrier();
      asm volatile("s_waitcnt lgkmcnt(0)" ::: "memory");
      __builtin_amdgcn_sched_barrier(0);
      __builtin_amdgcn_s_setprio(1);
#pragma unroll
      for (int mi = 0; mi < 4; mi++)
#pragma unroll
        for (int ni = 0; ni < 2; ni++) {
          accg[mi][ni] = mfma16(af[mi][0], bgf[ni][0], accg[mi][ni]);
          accg[mi][ni] = mfma16(af[mi][1], bgf[ni][1], accg[mi][ni]);
          accu[mi][ni] = mfma16(af[mi][0], buf2[ni][0], accu[mi][ni]);
          accu[mi][ni] = mfma16(af[mi][1], buf2[ni][1], accu[mi][ni]);
        }
      __builtin_amdgcn_s_setprio(0);
      if (T + 1 < NT) asm volatile("s_waitcnt vmcnt(6)" ::: "memory");
      else            asm volatile("s_waitcnt vmcnt(0)" ::: "memory");
      fence_barrier();
    }
    // ---- phase 1: A-half 1, B frags from registers ----
    {
      bf16x8 af[4][2];
#pragma unroll
      for (int mi = 0; mi < 4; mi++) {
        af[mi][0] = *(const bf16x8*)(sb + 16384 + rowA + mi * 2048 + c0);
        af[mi][1] = *(const bf16x8*)(sb + 16384 + rowA + mi * 2048 + (c0 ^ 64));
      }
      if (T + 1 < NT)
        stageU(bn, 16384, aB + (size_t)128 * DIM + (T + 1) * 64,
                          aB + (size_t)192 * DIM + (T + 1) * 64);
      if (T + 2 < NT)
        stageU(b, 0, aB + (T + 2) * 64, aB + (size_t)64 * DIM + (T + 2) * 64);
      asm volatile("" ::: "memory");
      __builtin_amdgcn_s_barrier();
      asm volatile("s_waitcnt lgkmcnt(0)" ::: "memory");
      __builtin_amdgcn_sched_barrier(0);
      __builtin_amdgcn_s_setprio(1);
#pragma unroll
      for (int mi = 0; mi < 4; mi++)
#pragma unroll
        for (int ni = 0; ni < 2; ni++) {
          accg[4 + mi][ni] = mfma16(af[mi][0], bgf[ni][0], accg[4 + mi][ni]);
          accg[4 + mi][ni] = mfma16(af[mi][1], bgf[ni][1], accg[4 + mi][ni]);
          accu[4 + mi][ni] = mfma16(af[mi][0], buf2[ni][0], accu[4 + mi][ni]);
          accu[4 + mi][ni] = mfma16(af[mi][1], buf2[ni][1], accu[4 + mi][ni]);
        }
      __builtin_amdgcn_s_setprio(0);
      if (T + 2 < NT)      asm volatile("s_waitcnt vmcnt(4)" ::: "memory");
      else if (T + 1 < NT) asm volatile("s_waitcnt vmcnt(2)" ::: "memory");
      fence_barrier();
    }
  }

  // epilogue: hact = silu(g)*u. C/D: col = lane&15, row = (lane>>4)*4 + reg.
  unsigned short* ob = hact + (size_t)e * CAP * HID;
#pragma unroll
  for (int mh = 0; mh < 2; mh++)
#pragma unroll
    for (int mi = 0; mi < 4; mi++)
#pragma unroll
      for (int r = 0; r < 4; r++) {
        const int row = m0 + mh * 128 + wr * 64 + mi * 16 + q * 4 + r;
        const size_t rb = (size_t)row * HID;
#pragma unroll
        for (int ni = 0; ni < 2; ni++) {
          const int col = n0 + wc * 32 + ni * 16 + li;
          const float g = accg[mh * 4 + mi][ni][r];
          const float u = accu[mh * 4 + mi][ni][r];
          ob[rb + col] = f2bf(g / (1.0f + __expf(-g)) * u);
        }
      }
}

// ---------------------------------------------------------------------------
// Down GEMM + fused gather/scale. Tile 128M x 128N, BK=64, 4 waves (2x2),
// per-wave 64x64. LDS 64 KiB (2 buf x {A 16K | B 16K}) -> 2 blocks/CU.
// One barrier-pair + 32 MFMA per K-tile; read-once frags (A 8 + B 8 b128).
// Stage: B(T+1)->bn pre-barrier, A(T+2)->b post-MFMA; tail vmcnt(4).
// ---------------------------------------------------------------------------
__global__ __launch_bounds__(256, 2)
void down_gemm2(const unsigned short* __restrict__ A,
                const unsigned short* __restrict__ Bt,
                const int* __restrict__ counts,
                const int* __restrict__ slot_token,
                const float* __restrict__ scores,
                float* __restrict__ y) {
  extern __shared__ __align__(16) char smem[];
  // grid 640 = 8 xcd * (8 cgl * 10 m)
  const int bid = blockIdx.x;
  const int xcd = bid & 7;
  const int slotb = bid >> 3;      // 0..79
  const int m = slotb % 10;
  const int cgl = slotb / 10;      // 0..7
  const int cg = xcd + 8 * cgl;    // 0..63
  const int n = cg % 8;
  const int e = cg / 8;

  const int cnt = counts[e];
  const int m0 = m * 128;
  if (m0 >= cnt) return;
  const int n0 = n * 128;

  const int t = threadIdx.x;
  const int lane = t & 63;
  const int w = t >> 6;
  const int wr = w >> 1;     // 0..1
  const int wc = w & 1;      // 0..1
  const int li = lane & 15;
  const int q = lane >> 4;

  const int sr8 = t >> 3;    // 0..31
  const int cLog = (t & 7) ^ (sr8 & 7);
  const unsigned short* aB = A  + ((size_t)e * CAP + m0 + sr8) * HID + cLog * 8;
  const unsigned short* bB = Bt + ((size_t)e * DIM + n0 + sr8) * HID + cLog * 8;

  auto stageA = [&](int bb, int koff) {
#pragma unroll
    for (int j = 0; j < 4; j++)
      async16(smem + bb * 32768 + j * 4096 + t * 16, aB + (size_t)j * 32 * HID + koff);
  };
  auto stageB = [&](int bb, int koff) {
#pragma unroll
    for (int j = 0; j < 4; j++)
      async16(smem + bb * 32768 + 16384 + j * 4096 + t * 16, bB + (size_t)j * 32 * HID + koff);
  };

  const int rowA = (wr * 64 + li) * 128;
  const int rowB = (wc * 64 + li) * 128;
  const int c0 = (q ^ (li & 7)) * 16;

  floatx4 acc[4][4] = {};

  constexpr int NT = HID / 64;  // 44 K-tiles

  // prologue: A(0)[4], B(0)[4], A(1)[4]; wait oldest 8.
  stageA(0, 0);
  stageB(0, 0);
  stageA(1, 64);
  asm volatile("s_waitcnt vmcnt(4)" ::: "memory");
  fence_barrier();

#pragma unroll 2
  for (int T = 0; T < NT; T++) {
    const int b = T & 1;
    const int bn = b ^ 1;
    char* sb = smem + b * 32768;
    bf16x8 af[4][2], bfr[4][2];
#pragma unroll
    for (int mi = 0; mi < 4; mi++) {
      af[mi][0] = *(const bf16x8*)(sb + rowA + mi * 2048 + c0);
      af[mi][1] = *(const bf16x8*)(sb + rowA + mi * 2048 + (c0 ^ 64));
    }
#pragma unroll
    for (int ni = 0; ni < 4; ni++) {
      bfr[ni][0] = *(const bf16x8*)(sb + 16384 + rowB + ni * 2048 + c0);
      bfr[ni][1] = *(const bf16x8*)(sb + 16384 + rowB + ni * 2048 + (c0 ^ 64));
    }
    if (T + 1 < NT) stageB(bn, (T + 1) * 64);
    asm volatile("" ::: "memory");
    __builtin_amdgcn_s_barrier();
    asm volatile("s_waitcnt lgkmcnt(0)" ::: "memory");
    __builtin_amdgcn_sched_barrier(0);
    __builtin_amdgcn_s_setprio(1);
#pragma unroll
    for (int mi = 0; mi < 4; mi++)
#pragma unroll
      for (int ni = 0; ni < 4; ni++) {
        acc[mi][ni] = mfma16(af[mi][0], bfr[ni][0], acc[mi][ni]);
        acc[mi][ni] = mfma16(af[mi][1], bfr[ni][1], acc[mi][ni]);
      }
    __builtin_amdgcn_s_setprio(0);
    if (T + 2 < NT) stageA(b, (T + 2) * 64);
    if (T + 2 < NT)      asm volatile("s_waitcnt vmcnt(4)" ::: "memory");
    else if (T + 1 < NT) asm volatile("s_waitcnt vmcnt(0)" ::: "memory");
    fence_barrier();
  }

  // epilogue: y[tok] = acc * score (row < cnt only)
#pragma unroll
  for (int mi = 0; mi < 4; mi++)
#pragma unroll
    for (int r = 0; r < 4; r++) {
      const int row = m0 + wr * 64 + mi * 16 + q * 4 + r;
      if (row < cnt) {
        const int tok = slot_token[e * CAP + row];
        const float s = scores[tok];
        float* yr = y + (size_t)tok * DIM;
#pragma unroll
        for (int ni = 0; ni < 4; ni++) {
          const int col = n0 + wc * 64 + ni * 16 + li;
          yr[col] = acc[mi][ni][r] * s;
        }
      }
    }
}

extern "C" void kernel_launch(void* const* d_in, const int* in_sizes, int n_in,
                              void* d_out, int out_size, void* d_ws, size_t ws_size,
                              hipStream_t stream) {
  const float* x      = (const float*)d_in[0];
  const int*   idx    = (const int*)d_in[1];
  const float* scores = (const float*)d_in[2];
  const float* Wg     = (const float*)d_in[3];
  const float* Wu     = (const float*)d_in[4];
  const float* Wd     = (const float*)d_in[5];
  float* y = (float*)d_out;

  const int idx_stride = (in_sizes[1] == 2 * N_TOK) ? 2 : 1;

  char* ws = (char*)d_ws;
  size_t off = 0;
  auto alloc = [&](size_t b) -> char* {
    char* p = ws + off;
    off += (b + 255) & ~(size_t)255;
    return p;
  };
  int* counts            = (int*)alloc(NEXP * 4);
  int* slot              = (int*)alloc((size_t)N_TOK * 4);
  int* slot_token        = (int*)alloc((size_t)NEXP * CAP * 4);
  unsigned short* xe     = (unsigned short*)alloc((size_t)NEXP * CAP * DIM * 2);
  unsigned short* hact   = (unsigned short*)alloc((size_t)NEXP * CAP * HID * 2);
  unsigned short* wg_t   = (unsigned short*)alloc((size_t)NEXP * DIM * HID * 2);
  unsigned short* wu_t   = (unsigned short*)alloc((size_t)NEXP * DIM * HID * 2);
  unsigned short* wd_t   = (unsigned short*)alloc((size_t)NEXP * DIM * HID * 2);
  (void)ws_size; (void)n_in; (void)out_size;

  static bool s_attr_done = false;
  if (!s_attr_done) {
    hipFuncSetAttribute((const void*)gateup_gemm2,
                        hipFuncAttributeMaxDynamicSharedMemorySize, 131072);
    hipFuncSetAttribute((const void*)down_gemm2,
                        hipFuncAttributeMaxDynamicSharedMemorySize, 65536);
    s_attr_done = true;
  }

  route_kernel<<<1, 256, 0, stream>>>(idx, idx_stride, slot, slot_token, counts);
  dispatch_kernel<<<N_TOK, 256, 0, stream>>>(x, slot, xe, y);

  // Wg,Wu: [d][h] -> [h][d] bf16 ;  Wd: [h][d] -> [d][h] bf16
  transpose_cvt<<<dim3(HID / 64, DIM / 64, NEXP), 256, 0, stream>>>(Wg, wg_t, DIM, HID);
  transpose_cvt<<<dim3(HID / 64, DIM / 64, NEXP), 256, 0, stream>>>(Wu, wu_t, DIM, HID);
  transpose_cvt<<<dim3(DIM / 64, HID / 64, NEXP), 256, 0, stream>>>(Wd, wd_t, HID, DIM);

  // fused gate+up: hact = silu(xe@Wg) * (xe@Wu)   [read-once frags, 2-phase]
  gateup_gemm2<<<8 * 22 * 5, 512, 131072, stream>>>(xe, wg_t, wu_t, counts, hact);
  // down + fused gather/scale: y[tok] = (hact @ Wd) * score  [2 blocks/CU]
  down_gemm2<<<8 * 8 * 10, 256, 65536, stream>>>(hact, wd_t, counts, slot_token, scores, y);
}